// Round 10
// baseline (427.480 us; speedup 1.0000x reference)
//
#include <hip/hip_runtime.h>
#include <math.h>

#define B_  8
#define S_  4096
#define D_  768     // DIM == D_INNER == 768
#define K_  16      // KK
#define C_  48      // CD
#define N_  16      // NS
#define M_  (B_*S_) // 32768 rows

typedef float  f32x4  __attribute__((ext_vector_type(4)));
typedef __bf16 bf16x8 __attribute__((ext_vector_type(8)));

__device__ __forceinline__ ushort f2bf(float f) {
  uint u = __builtin_bit_cast(uint, f);
  u += 0x7FFFu + ((u >> 16) & 1u);      // round-to-nearest-even
  return (ushort)(u >> 16);
}
__device__ __forceinline__ float bf2f(ushort h) {
  return __builtin_bit_cast(float, (uint)h << 16);
}

// ---------------- weights f32 -> bf16 (w1 = in_proj rows [0,768), w2 = out_proj)
__global__ __launch_bounds__(256)
void cvt_w(const float* __restrict__ w1, const float* __restrict__ w2,
           ushort* __restrict__ o1, ushort* __restrict__ o2) {
  const int i = blockIdx.x * 256 + threadIdx.x;      // 1152*256 = 2*147456
  const float* src; ushort* dst; int idx;
  if (i < 147456) { src = w1; dst = o1; idx = i; }
  else            { src = w2; dst = o2; idx = i - 147456; }
  float4 v = *reinterpret_cast<const float4*>(src + (size_t)idx * 4);
  ushort4 o;
  o.x = f2bf(v.x); o.y = f2bf(v.y); o.z = f2bf(v.z); o.w = f2bf(v.w);
  *reinterpret_cast<ushort4*>(dst + (size_t)idx * 4) = o;
}

// ---------------- GEMM1 (direct-to-register, no LDS, no barriers):
// u0T = (x @ W1^T + in_b) stored TRANSPOSED [c][l] bf16.
// Fragment addressing == previous LDS-linear layout: row = base+mf*16+lr, k = k0+lg*8.
__global__ __launch_bounds__(256)
void gemm1_direct(const float* __restrict__ X, const ushort* __restrict__ Wb,
                  const float* __restrict__ in_b, ushort* __restrict__ u0T)
{
  const int lin = blockIdx.x;
  const int swz = (lin & 7) * 192 + (lin >> 3);   // XCD swizzle (1536%8==0 bijective)
  const int bn  = (swz % 6) * 128;
  const int bm  = (swz / 6) * 128;

  const int tid  = threadIdx.x;
  const int wid  = tid >> 6, lane = tid & 63;
  const int wr   = wid >> 1, wc   = wid & 1;
  const int lr   = lane & 15, lg  = lane >> 4;

  const float*  xb = X  + (size_t)(bm + wr * 64 + lr) * 768 + lg * 8;
  const ushort* wb = Wb + (size_t)(bn + wc * 64 + lr) * 768 + lg * 8;
  const int fs = 16 * 768;                         // mf/nf fragment row stride

  f32x4 acc[4][4];
#pragma unroll
  for (int i = 0; i < 4; ++i)
#pragma unroll
    for (int j = 0; j < 4; ++j) acc[i][j] = (f32x4){0.f, 0.f, 0.f, 0.f};

  // 1-deep register prefetch (no barrier ever drains these)
  f32x4  pa0[4], pa1[4];
  bf16x8 pb[4];
#pragma unroll
  for (int mf = 0; mf < 4; ++mf) {
    pa0[mf] = *reinterpret_cast<const f32x4*>(xb + mf * fs);
    pa1[mf] = *reinterpret_cast<const f32x4*>(xb + mf * fs + 4);
  }
#pragma unroll
  for (int nf = 0; nf < 4; ++nf)
    pb[nf] = *reinterpret_cast<const bf16x8*>(wb + nf * fs);

  for (int k0 = 0; k0 < 768; k0 += 32) {
    bf16x8 ca[4], cb[4];
#pragma unroll
    for (int mf = 0; mf < 4; ++mf)
      ca[mf] = (bf16x8){(__bf16)pa0[mf][0], (__bf16)pa0[mf][1], (__bf16)pa0[mf][2], (__bf16)pa0[mf][3],
                        (__bf16)pa1[mf][0], (__bf16)pa1[mf][1], (__bf16)pa1[mf][2], (__bf16)pa1[mf][3]};
#pragma unroll
    for (int nf = 0; nf < 4; ++nf) cb[nf] = pb[nf];

    if (k0 + 32 < 768) {   // issue next K-step's loads; hidden under the MFMAs below
      const int kn = k0 + 32;
#pragma unroll
      for (int mf = 0; mf < 4; ++mf) {
        pa0[mf] = *reinterpret_cast<const f32x4*>(xb + mf * fs + kn);
        pa1[mf] = *reinterpret_cast<const f32x4*>(xb + mf * fs + kn + 4);
      }
#pragma unroll
      for (int nf = 0; nf < 4; ++nf)
        pb[nf] = *reinterpret_cast<const bf16x8*>(wb + nf * fs + kn);
    }

#pragma unroll
    for (int mf = 0; mf < 4; ++mf)
#pragma unroll
      for (int nf = 0; nf < 4; ++nf)
        acc[mf][nf] = __builtin_amdgcn_mfma_f32_16x16x32_bf16(ca[mf], cb[nf], acc[mf][nf], 0, 0, 0);
  }

  // epilogue: transposed store u0T[(b*768 + c)*4096 + l], 8B per lane
  const int b   = bm >> 12;
  const int l0g = (bm & 4095) + wr * 64;
#pragma unroll
  for (int nf = 0; nf < 4; ++nf) {
    const int cg = bn + wc * 64 + nf * 16 + lr;
    const float bv = in_b[cg];
    ushort* up = u0T + ((size_t)b * 768 + cg) * 4096 + l0g;
#pragma unroll
    for (int mf = 0; mf < 4; ++mf) {
      ushort4 o;
      o.x = f2bf(acc[mf][nf][0] + bv);
      o.y = f2bf(acc[mf][nf][1] + bv);
      o.z = f2bf(acc[mf][nf][2] + bv);
      o.w = f2bf(acc[mf][nf][3] + bv);
      *reinterpret_cast<ushort4*>(up + mf * 16 + lg * 4) = o;
    }
  }
}

// ---------------- GEMM2 (direct-to-register): out = yT @ W2^T + out_b  (f32 out)
__global__ __launch_bounds__(256)
void gemm2_direct(const ushort* __restrict__ A, const ushort* __restrict__ Bm,
                  const float* __restrict__ bias, float* __restrict__ Cc)
{
  const int lin = blockIdx.x;
  const int swz = (lin & 7) * 192 + (lin >> 3);
  const int bn  = (swz % 6) * 128;
  const int bm  = (swz / 6) * 128;

  const int tid  = threadIdx.x;
  const int wid  = tid >> 6, lane = tid & 63;
  const int wr   = wid >> 1, wc   = wid & 1;
  const int lr   = lane & 15, lg  = lane >> 4;

  const ushort* ab = A  + (size_t)(bm + wr * 64 + lr) * 768 + lg * 8;
  const ushort* wb = Bm + (size_t)(bn + wc * 64 + lr) * 768 + lg * 8;
  const int fs = 16 * 768;

  f32x4 acc[4][4];
#pragma unroll
  for (int i = 0; i < 4; ++i)
#pragma unroll
    for (int j = 0; j < 4; ++j) acc[i][j] = (f32x4){0.f, 0.f, 0.f, 0.f};

  bf16x8 pa[4], pb[4];
#pragma unroll
  for (int mf = 0; mf < 4; ++mf) pa[mf] = *reinterpret_cast<const bf16x8*>(ab + mf * fs);
#pragma unroll
  for (int nf = 0; nf < 4; ++nf) pb[nf] = *reinterpret_cast<const bf16x8*>(wb + nf * fs);

  for (int k0 = 0; k0 < 768; k0 += 32) {
    bf16x8 ca[4], cb[4];
#pragma unroll
    for (int mf = 0; mf < 4; ++mf) ca[mf] = pa[mf];
#pragma unroll
    for (int nf = 0; nf < 4; ++nf) cb[nf] = pb[nf];

    if (k0 + 32 < 768) {
      const int kn = k0 + 32;
#pragma unroll
      for (int mf = 0; mf < 4; ++mf) pa[mf] = *reinterpret_cast<const bf16x8*>(ab + mf * fs + kn);
#pragma unroll
      for (int nf = 0; nf < 4; ++nf) pb[nf] = *reinterpret_cast<const bf16x8*>(wb + nf * fs + kn);
    }

#pragma unroll
    for (int mf = 0; mf < 4; ++mf)
#pragma unroll
      for (int nf = 0; nf < 4; ++nf)
        acc[mf][nf] = __builtin_amdgcn_mfma_f32_16x16x32_bf16(ca[mf], cb[nf], acc[mf][nf], 0, 0, 0);
  }

#pragma unroll
  for (int nf = 0; nf < 4; ++nf) {
    const int n  = bn + wc * 64 + nf * 16 + lr;
    const float bv = bias[n];
#pragma unroll
    for (int mf = 0; mf < 4; ++mf) {
      const int m0 = bm + wr * 64 + mf * 16 + lg * 4;
#pragma unroll
      for (int r = 0; r < 4; ++r)
        Cc[(size_t)(m0 + r) * 768 + n] = acc[mf][nf][r] + bv;
    }
  }
}

// ---------------- fused middle (unchanged from R9, passing): conv3+silu via
// unconditional shfl + halo select, softplus(delta), einsum, d*d*u*s, [l][c] store.
#define YSP 70

__global__ __launch_bounds__(256)
void fuse_mid(const ushort* __restrict__ u0T, const float* __restrict__ delta,
              const float* __restrict__ Bt, const float* __restrict__ Ct,
              const float* __restrict__ Alog, const float* __restrict__ convw,
              const float* __restrict__ convb, const float* __restrict__ dbias,
              ushort* __restrict__ yT)
{
  __shared__ float  Gs [N_ * 64];       // [n][dl]  B*C products (4 KB)
  __shared__ float  Ak [C_ * N_];       // [c][n]   A rows (3 KB, broadcast reads)
  __shared__ ushort Ys [C_ * YSP];      // [c][dl]  result bounce (6.6 KB)
  __shared__ float  Wk0[C_], Wk1[C_], Wk2[C_], CB[C_], DB[C_];

  const int tid = threadIdx.x;
  const int wid = tid >> 6, lane = tid & 63;
  const int lt = blockIdx.x, k = blockIdx.y, b = blockIdx.z;
  const int l0 = lt * 64;

  for (int idx = tid; idx < N_ * 64; idx += 256) {
    const int n = idx >> 6, dl = idx & 63;
    const size_t gg = (((size_t)b * K_ + k) * N_ + n) * S_ + l0 + dl;
    Gs[idx] = Bt[gg] * Ct[gg];
  }
  for (int idx = tid; idx < C_ * N_; idx += 256)
    Ak[idx] = Alog[(size_t)k * C_ * N_ + idx];
  if (tid < C_) {
    Wk0[tid] = convw[(k * C_ + tid) * 9 + 1];   // only kw=1 column in-bounds (W=1, pad 1)
    Wk1[tid] = convw[(k * C_ + tid) * 9 + 4];
    Wk2[tid] = convw[(k * C_ + tid) * 9 + 7];
    CB [tid] = convb[k * C_ + tid];
    DB [tid] = dbias[k * C_ + tid];
  }
  __syncthreads();

  float g[N_];
#pragma unroll
  for (int n = 0; n < N_; ++n) g[n] = Gs[n * 64 + lane];

  const int  gl = l0 + lane;
  const size_t base = ((size_t)b * D_ + k * C_ + wid) * S_ + gl;
  const float*  dp = delta + base;
  const ushort* up = u0T + base;
  const size_t cs = (size_t)4 * S_;

  const bool edge_lo = (lane == 0);
  const bool edge_hi = (lane == 63);
  const int  hoff    = edge_lo ? -1 : 1;
  const bool h_ok    = (edge_lo && gl > 0) || (edge_hi && gl + 1 < S_);

  float dA = dp[0];
  float uA = bf2f(up[0]);
  float hA = h_ok ? bf2f(up[hoff]) : 0.f;
  float dB = dp[cs];
  float uB = bf2f(up[cs]);
  float hB = h_ok ? bf2f(up[cs + hoff]) : 0.f;

  for (int step = 0; step < 12; ++step) {
    const int c = step * 4 + wid;
    const float dcur = dA, u0v = uA, hv = hA;
    dA = dB; uA = uB; hA = hB;
    if (step < 10) {
      const size_t off = (size_t)(step + 2) * cs;
      dB = dp[off];
      uB = bf2f(up[off]);
      hB = h_ok ? bf2f(up[off + hoff]) : 0.f;
    }

    float a[N_];
#pragma unroll
    for (int n4i = 0; n4i < 4; ++n4i)   // broadcast ds_read_b128 x4 (uniform address)
      *reinterpret_cast<f32x4*>(&a[n4i * 4]) =
          *reinterpret_cast<const f32x4*>(&Ak[c * N_ + n4i * 4]);

    // conv neighbors: shuffles executed UNCONDITIONALLY by all 64 lanes, then select halo
    const float sm = __shfl(u0v, (lane + 63) & 63, 64);
    const float sp = __shfl(u0v, (lane + 1)  & 63, 64);
    const float um  = edge_lo ? hv : sm;
    const float upv = edge_hi ? hv : sp;

    const float dv = dcur + DB[c];
    const float d  = (dv > 15.f) ? dv : __logf(1.f + __expf(dv));   // softplus

    float xx = fmaf(Wk0[c], um, fmaf(Wk1[c], u0v, fmaf(Wk2[c], upv, CB[c])));
    const float u = xx * __builtin_amdgcn_rcpf(1.f + __expf(-xx));  // silu

    float s = 0.f;
#pragma unroll
    for (int n = 0; n < N_; ++n) s = fmaf(a[n], g[n], s);

    Ys[c * YSP + lane] = f2bf(d * d * u * s);
  }
  __syncthreads();

  // [l][c] store as packed uints (2 channels per store); incremental div (256 = 10*24+16)
  {
    uint* yTu = reinterpret_cast<uint*>(yT);
    int dl = tid / 24, j = tid - (tid / 24) * 24;
    for (int e = tid; e < 64 * 24; e += 256) {
      const uint lo = Ys[(2 * j    ) * YSP + dl];
      const uint hi = Ys[(2 * j + 1) * YSP + dl];
      yTu[((size_t)b * S_ + l0 + dl) * 384 + k * 24 + j] = lo | (hi << 16);
      dl += 10; j += 16; if (j >= 24) { j -= 24; dl += 1; }
    }
  }
}

extern "C" void kernel_launch(void* const* d_in, const int* in_sizes, int n_in,
                              void* d_out, int out_size, void* d_ws, size_t ws_size,
                              hipStream_t stream) {
  const float* x      = (const float*)d_in[0];
  const float* in_w   = (const float*)d_in[1];   // (1536,768) — only rows [0,768) used
  const float* in_b   = (const float*)d_in[2];
  const float* convw  = (const float*)d_in[3];
  const float* convb  = (const float*)d_in[4];
  const float* out_w  = (const float*)d_in[5];
  const float* out_b  = (const float*)d_in[6];
  const float* Alog   = (const float*)d_in[7];
  const float* delta  = (const float*)d_in[8];
  const float* Bt     = (const float*)d_in[9];
  const float* Ct     = (const float*)d_in[10];
  const float* dbias  = (const float*)d_in[11];
  float* out = (float*)d_out;

  ushort* u0T = (ushort*)d_ws;               // (B,768,S) bf16 — TRANSPOSED u0
  ushort* yTb = u0T + (size_t)M_ * D_;       // (B,S,768) bf16
  ushort* wb1 = yTb + (size_t)M_ * D_;
  ushort* wb2 = wb1 + (size_t)D_ * D_;

  cvt_w<<<1152, 256, 0, stream>>>(in_w, out_w, wb1, wb2);
  gemm1_direct<<<1536, 256, 0, stream>>>(x, wb1, in_b, u0T);
  fuse_mid<<<dim3(S_ / 64, K_, B_), 256, 0, stream>>>(u0T, delta, Bt, Ct, Alog,
                                                      convw, convb, dbias, yTb);
  gemm2_direct<<<1536, 256, 0, stream>>>(yTb, wb2, out_b, out);
}

// Round 11
// 236.919 us; speedup vs baseline: 1.8043x; 1.8043x over previous
//
#include <hip/hip_runtime.h>
#include <math.h>

#define B_  8
#define S_  4096
#define D_  768     // DIM == D_INNER == 768
#define K_  16      // KK
#define C_  48      // CD
#define N_  16      // NS
#define M_  (B_*S_) // 32768 rows

typedef float  f32x4  __attribute__((ext_vector_type(4)));
typedef __bf16 bf16x8 __attribute__((ext_vector_type(8)));

__device__ __forceinline__ ushort f2bf(float f) {
  uint u = __builtin_bit_cast(uint, f);
  u += 0x7FFFu + ((u >> 16) & 1u);      // round-to-nearest-even
  return (ushort)(u >> 16);
}
__device__ __forceinline__ float bf2f(ushort h) {
  return __builtin_bit_cast(float, (uint)h << 16);
}

// ---------------- weights f32 -> bf16 (w1 = in_proj rows [0,768), w2 = out_proj)
__global__ __launch_bounds__(256)
void cvt_w(const float* __restrict__ w1, const float* __restrict__ w2,
           ushort* __restrict__ o1, ushort* __restrict__ o2) {
  const int i = blockIdx.x * 256 + threadIdx.x;      // 1152*256 = 2*147456
  const float* src; ushort* dst; int idx;
  if (i < 147456) { src = w1; dst = o1; idx = i; }
  else            { src = w2; dst = o2; idx = i - 147456; }
  float4 v = *reinterpret_cast<const float4*>(src + (size_t)idx * 4);
  ushort4 o;
  o.x = f2bf(v.x); o.y = f2bf(v.y); o.z = f2bf(v.z); o.w = f2bf(v.w);
  *reinterpret_cast<ushort4*>(dst + (size_t)idx * 4) = o;
}

// ---------------- GEMM1: u0T = (x @ W1^T + in_b) stored TRANSPOSED [c][l] bf16.
// A = f32 x staged via global_load_lds into a CHUNK-SWIZZLED 16KB LDS tile
// (linear dest + pre-swizzled global src + XOR'd ds_read: rule-#21 both-sides),
// converted to bf16 at fragment-read. B = bf16 weights via global_load_lds.
__global__ __launch_bounds__(256)
void gemm1_f32lds(const float* __restrict__ X, const ushort* __restrict__ Wb,
                  const float* __restrict__ in_b, ushort* __restrict__ u0T)
{
  __shared__ __align__(16) float  As[128 * 32];   // 16 KB, [row][chunk^row&7] f32
  __shared__ __align__(16) ushort Bs[128 * 32];   // 8 KB, linear [row][k] bf16

  const int lin = blockIdx.x;
  const int swz = (lin & 7) * 192 + (lin >> 3);   // XCD swizzle (1536%8==0 bijective)
  const int bn  = (swz % 6) * 128;
  const int bm  = (swz / 6) * 128;

  const int tid  = threadIdx.x;
  const int wid  = tid >> 6, lane = tid & 63;
  const int wr   = wid >> 1, wc   = wid & 1;
  const int lr   = lane & 15, lg  = lane >> 4;
  const int srow = lane >> 2;                 // B staging: row within 16-row chunk
  const int scol = (lane & 3) * 8;            // B staging: k offset (8 bf16 = 16B)
  const int arow = lane >> 3;                 // A staging: row within 8-row chunk
  const int achk = (lane & 7) ^ (arow & 7);   // A staging: swizzled 16B chunk index

  f32x4 acc[4][4];
#pragma unroll
  for (int i = 0; i < 4; ++i)
#pragma unroll
    for (int j = 0; j < 4; ++j) acc[i][j] = (f32x4){0.f, 0.f, 0.f, 0.f};

  const f32x4* As4 = reinterpret_cast<const f32x4*>(As);

  for (int k0 = 0; k0 < 768; k0 += 32) {
    // A: 16 issues of 1KB (4/wave); lane L -> row j*8+L/8, global chunk (L%8)^(L/8&7)
#pragma unroll
    for (int jj = 0; jj < 4; ++jj) {
      const int j = wid * 4 + jj;
      const float* gx = X + (size_t)(bm + j * 8 + arow) * 768 + k0 + achk * 4;
      __builtin_amdgcn_global_load_lds(
          (const __attribute__((address_space(1))) void*)gx,
          (__attribute__((address_space(3))) void*)(As + j * 256), 16, 0, 0);
    }
    // B: 8 issues of 1KB (2/wave), linear
#pragma unroll
    for (int jj = 0; jj < 2; ++jj) {
      const int j = wid * 2 + jj;
      const ushort* gb = Wb + (size_t)(bn + j * 16 + srow) * 768 + k0 + scol;
      __builtin_amdgcn_global_load_lds(
          (const __attribute__((address_space(1))) void*)gb,
          (__attribute__((address_space(3))) void*)(Bs + j * 512), 16, 0, 0);
    }
    __syncthreads();

    // A-frags: two swizzled b128 f32 reads per mf, cvt to bf16 in registers
    bf16x8 ca[4], cb[4];
#pragma unroll
    for (int mf = 0; mf < 4; ++mf) {
      const int row = wr * 64 + mf * 16 + lr;
      const int rs  = lr & 7;                       // row&7 (wr*64, mf*16 ≡ 0 mod 8)
      const f32x4 v0 = As4[row * 8 + ((2 * lg)     ^ rs)];
      const f32x4 v1 = As4[row * 8 + ((2 * lg + 1) ^ rs)];
      ca[mf] = (bf16x8){(__bf16)v0[0], (__bf16)v0[1], (__bf16)v0[2], (__bf16)v0[3],
                        (__bf16)v1[0], (__bf16)v1[1], (__bf16)v1[2], (__bf16)v1[3]};
    }
    const int bb = (wc * 64 + lr) * 32 + lg * 8;
#pragma unroll
    for (int nf = 0; nf < 4; ++nf)
      cb[nf] = *reinterpret_cast<const bf16x8*>(&Bs[bb + nf * 512]);

#pragma unroll
    for (int mf = 0; mf < 4; ++mf)
#pragma unroll
      for (int nf = 0; nf < 4; ++nf)
        acc[mf][nf] = __builtin_amdgcn_mfma_f32_16x16x32_bf16(ca[mf], cb[nf], acc[mf][nf], 0, 0, 0);
    __syncthreads();
  }

  // epilogue: transposed store u0T[(b*768 + c)*4096 + l], 8B per lane (R9-identical)
  const int b   = bm >> 12;
  const int l0g = (bm & 4095) + wr * 64;
#pragma unroll
  for (int nf = 0; nf < 4; ++nf) {
    const int cg = bn + wc * 64 + nf * 16 + lr;
    const float bv = in_b[cg];
    ushort* up = u0T + ((size_t)b * 768 + cg) * 4096 + l0g;
#pragma unroll
    for (int mf = 0; mf < 4; ++mf) {
      ushort4 o;
      o.x = f2bf(acc[mf][nf][0] + bv);
      o.y = f2bf(acc[mf][nf][1] + bv);
      o.z = f2bf(acc[mf][nf][2] + bv);
      o.w = f2bf(acc[mf][nf][3] + bv);
      *reinterpret_cast<ushort4*>(up + mf * 16 + lg * 4) = o;
    }
  }
}

// ---------------- fused middle (R9, passing): conv3+silu via unconditional shfl +
// halo select, softplus(delta), einsum, d*d*u*s, [l][c] store.
#define YSP 70

__global__ __launch_bounds__(256)
void fuse_mid(const ushort* __restrict__ u0T, const float* __restrict__ delta,
              const float* __restrict__ Bt, const float* __restrict__ Ct,
              const float* __restrict__ Alog, const float* __restrict__ convw,
              const float* __restrict__ convb, const float* __restrict__ dbias,
              ushort* __restrict__ yT)
{
  __shared__ float  Gs [N_ * 64];       // [n][dl]  B*C products (4 KB)
  __shared__ float  Ak [C_ * N_];       // [c][n]   A rows (3 KB, broadcast reads)
  __shared__ ushort Ys [C_ * YSP];      // [c][dl]  result bounce (6.6 KB)
  __shared__ float  Wk0[C_], Wk1[C_], Wk2[C_], CB[C_], DB[C_];

  const int tid = threadIdx.x;
  const int wid = tid >> 6, lane = tid & 63;
  const int lt = blockIdx.x, k = blockIdx.y, b = blockIdx.z;
  const int l0 = lt * 64;

  for (int idx = tid; idx < N_ * 64; idx += 256) {
    const int n = idx >> 6, dl = idx & 63;
    const size_t gg = (((size_t)b * K_ + k) * N_ + n) * S_ + l0 + dl;
    Gs[idx] = Bt[gg] * Ct[gg];
  }
  for (int idx = tid; idx < C_ * N_; idx += 256)
    Ak[idx] = Alog[(size_t)k * C_ * N_ + idx];
  if (tid < C_) {
    Wk0[tid] = convw[(k * C_ + tid) * 9 + 1];   // only kw=1 column in-bounds (W=1, pad 1)
    Wk1[tid] = convw[(k * C_ + tid) * 9 + 4];
    Wk2[tid] = convw[(k * C_ + tid) * 9 + 7];
    CB [tid] = convb[k * C_ + tid];
    DB [tid] = dbias[k * C_ + tid];
  }
  __syncthreads();

  float g[N_];
#pragma unroll
  for (int n = 0; n < N_; ++n) g[n] = Gs[n * 64 + lane];

  const int  gl = l0 + lane;
  const size_t base = ((size_t)b * D_ + k * C_ + wid) * S_ + gl;
  const float*  dp = delta + base;
  const ushort* up = u0T + base;
  const size_t cs = (size_t)4 * S_;

  const bool edge_lo = (lane == 0);
  const bool edge_hi = (lane == 63);
  const int  hoff    = edge_lo ? -1 : 1;
  const bool h_ok    = (edge_lo && gl > 0) || (edge_hi && gl + 1 < S_);

  float dA = dp[0];
  float uA = bf2f(up[0]);
  float hA = h_ok ? bf2f(up[hoff]) : 0.f;
  float dB = dp[cs];
  float uB = bf2f(up[cs]);
  float hB = h_ok ? bf2f(up[cs + hoff]) : 0.f;

  for (int step = 0; step < 12; ++step) {
    const int c = step * 4 + wid;
    const float dcur = dA, u0v = uA, hv = hA;
    dA = dB; uA = uB; hA = hB;
    if (step < 10) {
      const size_t off = (size_t)(step + 2) * cs;
      dB = dp[off];
      uB = bf2f(up[off]);
      hB = h_ok ? bf2f(up[off + hoff]) : 0.f;
    }

    float a[N_];
#pragma unroll
    for (int n4i = 0; n4i < 4; ++n4i)   // broadcast ds_read_b128 x4 (uniform address)
      *reinterpret_cast<f32x4*>(&a[n4i * 4]) =
          *reinterpret_cast<const f32x4*>(&Ak[c * N_ + n4i * 4]);

    // conv neighbors: shuffles executed UNCONDITIONALLY by all 64 lanes, then select halo
    const float sm = __shfl(u0v, (lane + 63) & 63, 64);
    const float sp = __shfl(u0v, (lane + 1)  & 63, 64);
    const float um  = edge_lo ? hv : sm;
    const float upv = edge_hi ? hv : sp;

    const float dv = dcur + DB[c];
    const float d  = (dv > 15.f) ? dv : __logf(1.f + __expf(dv));   // softplus

    float xx = fmaf(Wk0[c], um, fmaf(Wk1[c], u0v, fmaf(Wk2[c], upv, CB[c])));
    const float u = xx * __builtin_amdgcn_rcpf(1.f + __expf(-xx));  // silu

    float s = 0.f;
#pragma unroll
    for (int n = 0; n < N_; ++n) s = fmaf(a[n], g[n], s);

    Ys[c * YSP + lane] = f2bf(d * d * u * s);
  }
  __syncthreads();

  // [l][c] store as packed uints (2 channels per store); incremental div (256 = 10*24+16)
  {
    uint* yTu = reinterpret_cast<uint*>(yT);
    int dl = tid / 24, j = tid - (tid / 24) * 24;
    for (int e = tid; e < 64 * 24; e += 256) {
      const uint lo = Ys[(2 * j    ) * YSP + dl];
      const uint hi = Ys[(2 * j + 1) * YSP + dl];
      yTu[((size_t)b * S_ + l0 + dl) * 384 + k * 24 + j] = lo | (hi << 16);
      dl += 10; j += 16; if (j >= 24) { j -= 24; dl += 1; }
    }
  }
}

// ---------------- GEMM2 (m97 structure, gload_lds — proven ~58 µs): out = yT @ W2^T + out_b
__global__ __launch_bounds__(256)
void gemm_mfma_bt(const ushort* __restrict__ A, const ushort* __restrict__ Bm,
                  const float* __restrict__ bias, float* __restrict__ Cc)
{
  __shared__ ushort As[128 * 32];
  __shared__ ushort Bs[128 * 32];

  const int lin = blockIdx.x;
  const int swz = (lin & 7) * 192 + (lin >> 3);
  const int bn  = (swz % 6) * 128;
  const int bm  = (swz / 6) * 128;

  const int tid  = threadIdx.x;
  const int wid  = tid >> 6, lane = tid & 63;
  const int wr   = wid >> 1, wc   = wid & 1;
  const int lr   = lane & 15, lg  = lane >> 4;
  const int srow = lane >> 2;
  const int scol = (lane & 3) * 8;

  f32x4 acc[4][4];
#pragma unroll
  for (int i = 0; i < 4; ++i)
#pragma unroll
    for (int j = 0; j < 4; ++j) acc[i][j] = (f32x4){0.f, 0.f, 0.f, 0.f};

  for (int k0 = 0; k0 < 768; k0 += 32) {
#pragma unroll
    for (int jj = 0; jj < 2; ++jj) {
      const int j = wid * 2 + jj;
      const ushort* ga = A  + (size_t)(bm + j * 16 + srow) * 768 + k0 + scol;
      __builtin_amdgcn_global_load_lds(
          (const __attribute__((address_space(1))) void*)ga,
          (__attribute__((address_space(3))) void*)(As + j * 512), 16, 0, 0);
      const ushort* gb = Bm + (size_t)(bn + j * 16 + srow) * 768 + k0 + scol;
      __builtin_amdgcn_global_load_lds(
          (const __attribute__((address_space(1))) void*)gb,
          (__attribute__((address_space(3))) void*)(Bs + j * 512), 16, 0, 0);
    }
    __syncthreads();

    bf16x8 af[4], bfr[4];
    const int ab = (wr * 64 + lr) * 32 + lg * 8;
    const int bb = (wc * 64 + lr) * 32 + lg * 8;
#pragma unroll
    for (int mf = 0; mf < 4; ++mf) af[mf]  = *reinterpret_cast<const bf16x8*>(&As[ab + mf * 512]);
#pragma unroll
    for (int nf = 0; nf < 4; ++nf) bfr[nf] = *reinterpret_cast<const bf16x8*>(&Bs[bb + nf * 512]);
#pragma unroll
    for (int mf = 0; mf < 4; ++mf)
#pragma unroll
      for (int nf = 0; nf < 4; ++nf)
        acc[mf][nf] = __builtin_amdgcn_mfma_f32_16x16x32_bf16(af[mf], bfr[nf], acc[mf][nf], 0, 0, 0);
    __syncthreads();
  }

#pragma unroll
  for (int nf = 0; nf < 4; ++nf) {
    const int n  = bn + wc * 64 + nf * 16 + lr;
    const float bv = bias[n];
#pragma unroll
    for (int mf = 0; mf < 4; ++mf) {
      const int m0 = bm + wr * 64 + mf * 16 + lg * 4;
#pragma unroll
      for (int r = 0; r < 4; ++r)
        Cc[(size_t)(m0 + r) * 768 + n] = acc[mf][nf][r] + bv;
    }
  }
}

extern "C" void kernel_launch(void* const* d_in, const int* in_sizes, int n_in,
                              void* d_out, int out_size, void* d_ws, size_t ws_size,
                              hipStream_t stream) {
  const float* x      = (const float*)d_in[0];
  const float* in_w   = (const float*)d_in[1];   // (1536,768) — only rows [0,768) used
  const float* in_b   = (const float*)d_in[2];
  const float* convw  = (const float*)d_in[3];
  const float* convb  = (const float*)d_in[4];
  const float* out_w  = (const float*)d_in[5];
  const float* out_b  = (const float*)d_in[6];
  const float* Alog   = (const float*)d_in[7];
  const float* delta  = (const float*)d_in[8];
  const float* Bt     = (const float*)d_in[9];
  const float* Ct     = (const float*)d_in[10];
  const float* dbias  = (const float*)d_in[11];
  float* out = (float*)d_out;

  ushort* u0T = (ushort*)d_ws;               // (B,768,S) bf16 — TRANSPOSED u0
  ushort* yTb = u0T + (size_t)M_ * D_;       // (B,S,768) bf16
  ushort* wb1 = yTb + (size_t)M_ * D_;
  ushort* wb2 = wb1 + (size_t)D_ * D_;

  cvt_w<<<1152, 256, 0, stream>>>(in_w, out_w, wb1, wb2);
  gemm1_f32lds<<<1536, 256, 0, stream>>>(x, wb1, in_b, u0T);
  fuse_mid<<<dim3(S_ / 64, K_, B_), 256, 0, stream>>>(u0T, delta, Bt, Ct, Alog,
                                                      convw, convb, dbias, yTb);
  gemm_mfma_bt<<<1536, 256, 0, stream>>>(yTb, wb2, out_b, out);
}